// Round 12
// baseline (756.162 us; speedup 1.0000x reference)
//
#include <hip/hip_runtime.h>

#define NTRAIN 65536
#define NQ     2048
#define KD     512
#define KNN    5

// ---------------- filter config: 256q x 2048t per block, 16 waves ----------------
#define QT2 256                  // queries per block
#define TPB 2048                 // train rows per block
#define CH 256                   // chunk size (fold granularity)
#define NGRP (NTRAIN / TPB)      // 32 train groups
#define NQT2 (NQ / QT2)          // 8 query tiles
#define NSLOT (NGRP * KNN)       // 160 cand entries per query
#define NSTEPS 128               // 8 chunks x 16 k-steps
#define MARGIN 2.0f
#define CAP 128

typedef short short8 __attribute__((ext_vector_type(8)));
typedef float f32x4 __attribute__((ext_vector_type(4)));

__device__ inline unsigned short f2bf(float f) {
    unsigned u = __float_as_uint(f);
    unsigned r = u + 0x7fffu + ((u >> 16) & 1u);
    return (unsigned short)(r >> 16);
}

template<int KK>
__device__ inline void ins5(float (&bd)[KK], int (&bi)[KK], float nd, int ni) {
    if (nd < bd[KK-1] || (nd == bd[KK-1] && ni < bi[KK-1])) {
#pragma unroll
        for (int k = 0; k < KK; ++k) {
            bool sw = (nd < bd[k]) || (nd == bd[k] && ni < bi[k]);
            float od = bd[k]; int oi = bi[k];
            bd[k] = sw ? nd : od; bi[k] = sw ? ni : oi;
            nd = sw ? od : nd;    ni = sw ? oi : ni;
        }
    }
}

__device__ inline void ins5v(float (&b5)[KNN], float v) {
    if (v < b5[KNN-1]) {
#pragma unroll
        for (int k = 0; k < KNN; ++k) {
            bool sw = v < b5[k];
            float o = b5[k];
            b5[k] = sw ? v : o;
            v = sw ? o : v;
        }
    }
}

// ---------------- t2: EXACT round-1 arithmetic (proven r4-r11) ----------------
__global__ __launch_bounds__(256)
void t2_kernel(const float* __restrict__ xt, float* __restrict__ t2) {
    int row  = blockIdx.x * 4 + (threadIdx.x >> 6);
    int lane = threadIdx.x & 63;
    const float4* p = (const float4*)(xt + (size_t)row * KD);
    float s = 0.f;
#pragma unroll
    for (int c = 0; c < 2; ++c) {
        float4 v = p[lane + c * 64];
        s += v.x * v.x + v.y * v.y + v.z * v.z + v.w * v.w;
    }
#pragma unroll
    for (int off = 32; off; off >>= 1) s += __shfl_down(s, off);
    if (lane == 0) t2[row] = s;
}

// ---------------- conv: fp32 row-major -> bf16 frag-major "units" (proven r10) ----------------
__global__ __launch_bounds__(256)
void conv_perm_kernel(const float* __restrict__ in, unsigned short* __restrict__ outp) {
    __shared__ unsigned short tile[16][512];      // 16 KB
    const int rg = blockIdx.x, t = threadIdx.x;
    const int row_l = t >> 4, sub = t & 15;

    const float* rp = in + ((size_t)rg * 16 + row_l) * KD + sub * 4;
#pragma unroll
    for (int j = 0; j < 8; ++j) {
        float4 v = *(const float4*)(rp + j * 64);
        unsigned short us[4] = { f2bf(v.x), f2bf(v.y), f2bf(v.z), f2bf(v.w) };
        *(unsigned long long*)&tile[row_l][sub * 4 + j * 64] = *(const unsigned long long*)us;
    }
    __syncthreads();

    const int kt = t >> 4;
    unsigned short* ub = outp + (size_t)(((rg >> 4) * 16 + kt) * 16 + (rg & 15)) * 512;
#pragma unroll
    for (int i = 0; i < 4; ++i) {
        int l = sub * 4 + i;
        *(uint4*)(ub + l * 8) = *(const uint4*)&tile[l & 15][kt * 32 + ((l >> 4) << 3)];
    }
}

// ---------------- filter: A reg->LDS dbuf (1 barrier/step), B direct-to-reg ----------------
__global__ __launch_bounds__(1024)
void knn_filter(const unsigned short* __restrict__ xperm, const unsigned short* __restrict__ xtperm,
                const float* __restrict__ t2g,
                float* __restrict__ candD, int* __restrict__ candI) {
    __shared__ __align__(16) char smem[81920];    // A dbuf 32KB | merge 80KB (aliased)

    const int tid  = threadIdx.x;
    const int w    = tid >> 6, lane = tid & 63;
    const int wm   = w & 3,  wn = w >> 2;         // wm: train quarter(64), wn: query quarter(64)
    const int lrow = lane & 15, lhi = lane >> 4;

    const int qt   = blockIdx.x & 7;              // qt == XCD -> x slice L2-resident
    const int grp  = blockIdx.x >> 3;             // 0..31
    const int q0   = qt * QT2;
    const int row0 = grp * TPB;

    const char* Au = (const char*)xtperm + (size_t)grp * 2097152;   // 8*16*16*1024
    const char* Bu = (const char*)xperm  + (size_t)qt  * 262144;    // 16*16*1024
    const int laneOff = lane * 16;

    char* const Ab0 = smem;                       // 16 KB (16 units)
    char* const Ab1 = smem + 16384;               // 16 KB

    f32x4 acc[4][4];
#pragma unroll
    for (int m = 0; m < 4; ++m)
#pragma unroll
        for (int n = 0; n < 4; ++n) acc[m][n] = 0.f;

    float bd[4][KNN]; int bi[4][KNN];
#pragma unroll
    for (int n = 0; n < 4; ++n)
#pragma unroll
        for (int k = 0; k < KNN; ++k) { bd[n][k] = 3.4e38f; bi[n][k] = 0x7fffffff; }

    // prologue: wave w stages A unit w of step 0, prefetch step 1 into rgA
    uint4 rgA = *(const uint4*)(Au + (size_t)(0 * 16 + w) * 1024 + laneOff);
    *(uint4*)(Ab0 + w * 1024 + laneOff) = rgA;
    rgA = *(const uint4*)(Au + (size_t)(1 * 16 + w) * 1024 + laneOff);
    __syncthreads();

    for (int s = 0; s < NSTEPS; ++s) {
        char* const bufR = (s & 1) ? Ab1 : Ab0;
        char* const bufW = (s & 1) ? Ab0 : Ab1;

        // write A(s+1) (loaded last step) to the other buffer; prefetch A(s+2)
        if (s + 1 < NSTEPS) *(uint4*)(bufW + w * 1024 + laneOff) = rgA;
        if (s + 2 < NSTEPS)
            rgA = *(const uint4*)(Au + (size_t)((s + 2) * 16 + w) * 1024 + laneOff);

        const int kt = s & 15;
        const char* Bk = Bu + (size_t)((kt * 16) + wn * 4) * 1024 + laneOff;
        short8 b0 = *(const short8*)(Bk);
        short8 b1 = *(const short8*)(Bk + 1024);
        short8 b2 = *(const short8*)(Bk + 2048);
        short8 b3 = *(const short8*)(Bk + 3072);

        short8 a0 = *(const short8*)(bufR + (wm * 4 + 0) * 1024 + laneOff);
        short8 a1 = *(const short8*)(bufR + (wm * 4 + 1) * 1024 + laneOff);
        short8 a2 = *(const short8*)(bufR + (wm * 4 + 2) * 1024 + laneOff);
        short8 a3 = *(const short8*)(bufR + (wm * 4 + 3) * 1024 + laneOff);

        acc[0][0] = __builtin_amdgcn_mfma_f32_16x16x32_bf16(a0, b0, acc[0][0], 0, 0, 0);
        acc[0][1] = __builtin_amdgcn_mfma_f32_16x16x32_bf16(a0, b1, acc[0][1], 0, 0, 0);
        acc[0][2] = __builtin_amdgcn_mfma_f32_16x16x32_bf16(a0, b2, acc[0][2], 0, 0, 0);
        acc[0][3] = __builtin_amdgcn_mfma_f32_16x16x32_bf16(a0, b3, acc[0][3], 0, 0, 0);
        acc[1][0] = __builtin_amdgcn_mfma_f32_16x16x32_bf16(a1, b0, acc[1][0], 0, 0, 0);
        acc[1][1] = __builtin_amdgcn_mfma_f32_16x16x32_bf16(a1, b1, acc[1][1], 0, 0, 0);
        acc[1][2] = __builtin_amdgcn_mfma_f32_16x16x32_bf16(a1, b2, acc[1][2], 0, 0, 0);
        acc[1][3] = __builtin_amdgcn_mfma_f32_16x16x32_bf16(a1, b3, acc[1][3], 0, 0, 0);
        acc[2][0] = __builtin_amdgcn_mfma_f32_16x16x32_bf16(a2, b0, acc[2][0], 0, 0, 0);
        acc[2][1] = __builtin_amdgcn_mfma_f32_16x16x32_bf16(a2, b1, acc[2][1], 0, 0, 0);
        acc[2][2] = __builtin_amdgcn_mfma_f32_16x16x32_bf16(a2, b2, acc[2][2], 0, 0, 0);
        acc[2][3] = __builtin_amdgcn_mfma_f32_16x16x32_bf16(a2, b3, acc[2][3], 0, 0, 0);
        acc[3][0] = __builtin_amdgcn_mfma_f32_16x16x32_bf16(a3, b0, acc[3][0], 0, 0, 0);
        acc[3][1] = __builtin_amdgcn_mfma_f32_16x16x32_bf16(a3, b1, acc[3][1], 0, 0, 0);
        acc[3][2] = __builtin_amdgcn_mfma_f32_16x16x32_bf16(a3, b2, acc[3][2], 0, 0, 0);
        acc[3][3] = __builtin_amdgcn_mfma_f32_16x16x32_bf16(a3, b3, acc[3][3], 0, 0, 0);

        // wave-local chunk fold (t2 direct; 8x per kernel)
        if ((s & 15) == 15) {
            const int c0  = row0 + (s >> 4) * CH;
            const int rbl = wm * 64 + lhi * 4;
#pragma unroll
            for (int m = 0; m < 4; ++m) {
                const float4 t2v = *(const float4*)(t2g + c0 + rbl + m * 16);
#pragma unroll
                for (int n = 0; n < 4; ++n)
#pragma unroll
                    for (int r2 = 0; r2 < 4; ++r2) {
                        float sc = fmaf(-2.f, acc[m][n][r2], (&t2v.x)[r2]);
                        ins5(bd[n], bi[n], sc, c0 + rbl + m * 16 + r2);
                    }
            }
#pragma unroll
            for (int m = 0; m < 4; ++m)
#pragma unroll
                for (int n = 0; n < 4; ++n) acc[m][n] = 0.f;
        }

        __syncthreads();   // buffer handoff (reads of bufR done; bufW visible next step)
    }

    // ---- block merge: 16 slots x top-5 per query, two 128-query half passes (r10-proven) ----
    float* MD = (float*)smem;                      // [128][80] = 40 KB
    int*   MI = (int*)(smem + 40960);              // [128][80] = 40 KB
    const int slot = wm * 4 + lhi;                 // 0..15
#pragma unroll
    for (int half = 0; half < 2; ++half) {
        __syncthreads();
#pragma unroll
        for (int n = 0; n < 4; ++n) {
            const int ql = wn * 64 + n * 16 + lrow;    // 0..255
            if ((ql >> 7) == half) {
#pragma unroll
                for (int k = 0; k < KNN; ++k) {
                    MD[(ql & 127) * 80 + slot * KNN + k] = bd[n][k];
                    MI[(ql & 127) * 80 + slot * KNN + k] = bi[n][k];
                }
            }
        }
        __syncthreads();
        if (tid < 128) {
            float fd[KNN]; int fi[KNN];
#pragma unroll
            for (int k = 0; k < KNN; ++k) { fd[k] = 3.4e38f; fi[k] = 0x7fffffff; }
            for (int j = 0; j < 16 * KNN; ++j) ins5(fd, fi, MD[tid * 80 + j], MI[tid * 80 + j]);
            size_t base = ((size_t)(q0 + half * 128 + tid) * NGRP + grp) * KNN;
#pragma unroll
            for (int k = 0; k < KNN; ++k) { candD[base + k] = fd[k]; candI[base + k] = fi[k]; }
        }
    }
}

// ---------------- refine: global approx top-5 -> tight T -> exact rerank -> vote ----------
__global__ __launch_bounds__(256)
void knn_refine(const float* __restrict__ x, const float* __restrict__ xt,
                const float* __restrict__ t2,
                const float* __restrict__ candD, const int* __restrict__ candI,
                const int* __restrict__ y, int* __restrict__ out) {
    __shared__ float sv[256 * KNN];
    __shared__ float sv2[64 * KNN];
    __shared__ float xl[KD];
    __shared__ int   lidx[CAP];
    __shared__ float lex[CAP];
    __shared__ int   lcount;
    __shared__ float sT;

    const int q = blockIdx.x, tid = threadIdx.x;
    const float* cd = candD + (size_t)q * NSLOT;
    const int*   ci = candI + (size_t)q * NSLOT;

    for (int i = tid; i < KD; i += 256) xl[i] = x[(size_t)q * KD + i];

    float b5[KNN];
#pragma unroll
    for (int k = 0; k < KNN; ++k) b5[k] = 3.4e38f;
    for (int j = tid; j < NSLOT; j += 256) ins5v(b5, cd[j]);
#pragma unroll
    for (int k = 0; k < KNN; ++k) sv[tid * KNN + k] = b5[k];
    __syncthreads();

    if (tid < 64) {
#pragma unroll
        for (int k = 0; k < KNN; ++k) b5[k] = 3.4e38f;
        for (int t = 0; t < 4; ++t)
#pragma unroll
            for (int k = 0; k < KNN; ++k) ins5v(b5, sv[(tid * 4 + t) * KNN + k]);
#pragma unroll
        for (int k = 0; k < KNN; ++k) sv2[tid * KNN + k] = b5[k];
    }
    __syncthreads();

    if (tid == 0) {
#pragma unroll
        for (int k = 0; k < KNN; ++k) b5[k] = 3.4e38f;
        for (int j = 0; j < 64 * KNN; ++j) ins5v(b5, sv2[j]);
        sT = b5[KNN - 1] + MARGIN;
        lcount = 0;
    }
    __syncthreads();
    float T = sT;

    for (int j = tid; j < NSLOT; j += 256) {
        if (cd[j] <= T) {
            int p = atomicAdd(&lcount, 1);
            if (p < CAP) lidx[p] = ci[j];
        }
    }
    __syncthreads();
    int Q = min(lcount, CAP);

    for (int j = tid; j < Q; j += 256) {
        int c = lidx[j];
        const float* tr = xt + (size_t)c * KD;
        float s = 0.f;
        for (int k = 0; k < KD; ++k) s = fmaf(xl[k], tr[k], s);
        lex[j] = fmaf(-2.f, s, t2[c]);
    }
    __syncthreads();

    if (tid == 0) {
        bool is64 = true;
#pragma unroll
        for (int i = 1; i < 64; i += 2) is64 = is64 && (y[i] == 0);
        float fd[KNN]; int fi[KNN];
#pragma unroll
        for (int k = 0; k < KNN; ++k) { fd[k] = 3.4e38f; fi[k] = 0x7fffffff; }
        for (int j = 0; j < Q; ++j) ins5(fd, fi, lex[j], lidx[j]);
        int lab[KNN];
#pragma unroll
        for (int k = 0; k < KNN; ++k) lab[k] = is64 ? y[2 * fi[k]] : y[fi[k]];
        int bestLab = 0x7fffffff, bestC = 0;
#pragma unroll
        for (int i = 0; i < KNN; ++i) {
            int c = 0;
#pragma unroll
            for (int j = 0; j < KNN; ++j) c += (lab[j] == lab[i]);
            if (c > bestC || (c == bestC && lab[i] < bestLab)) { bestC = c; bestLab = lab[i]; }
        }
        out[q] = bestLab;
    }
}

// =================== round-1 fp32 fallback (small ws) ===================
#define FB_QT 64
#define FB_TT 64
#define FB_KT 32
#define FB_NCHUNK 32
#define FB_CHUNK (NTRAIN / FB_NCHUNK)

__global__ __launch_bounds__(256)
void fb_knn_partial(const float* __restrict__ x, const float* __restrict__ xt,
                    const float* __restrict__ t2,
                    float* __restrict__ candD, int* __restrict__ candI) {
    __shared__ __align__(16) float smem[FB_QT * 81 * 2];
    float (*Xs)[FB_QT + 4] = (float (*)[FB_QT + 4])smem;
    float (*Ts)[FB_TT + 4] = (float (*)[FB_TT + 4])(smem + FB_KT * (FB_QT + 4));
    float (*MD)[81]     = (float (*)[81])smem;
    int   (*MI)[81]     = (int   (*)[81])(smem + FB_QT * 81);

    const int tid = threadIdx.x;
    const int tx = tid & 15, ty = tid >> 4;
    const int q0 = blockIdx.x * FB_QT;
    const int c0 = blockIdx.y * FB_CHUNK;
    const int sq = tid >> 2, sc = tid & 3;

    float bd[4][KNN]; int bi_[4][KNN];
#pragma unroll
    for (int i = 0; i < 4; ++i)
#pragma unroll
        for (int k = 0; k < KNN; ++k) { bd[i][k] = 3.4e38f; bi_[i][k] = 0x7fffffff; }

    const float* xrow = x + (size_t)(q0 + sq) * KD;

    for (int s = 0; s < FB_CHUNK; s += FB_TT) {
        float acc[4][4];
#pragma unroll
        for (int i = 0; i < 4; ++i)
#pragma unroll
            for (int j = 0; j < 4; ++j) acc[i][j] = 0.f;
        const float* trow = xt + (size_t)(c0 + s + sq) * KD;
        for (int kt = 0; kt < KD; kt += FB_KT) {
            float4 xv0 = *(const float4*)(xrow + kt + sc * 8);
            float4 xv1 = *(const float4*)(xrow + kt + sc * 8 + 4);
            float4 tv0 = *(const float4*)(trow + kt + sc * 8);
            float4 tv1 = *(const float4*)(trow + kt + sc * 8 + 4);
            __syncthreads();
            Xs[sc*8+0][sq] = xv0.x; Xs[sc*8+1][sq] = xv0.y;
            Xs[sc*8+2][sq] = xv0.z; Xs[sc*8+3][sq] = xv0.w;
            Xs[sc*8+4][sq] = xv1.x; Xs[sc*8+5][sq] = xv1.y;
            Xs[sc*8+6][sq] = xv1.z; Xs[sc*8+7][sq] = xv1.w;
            Ts[sc*8+0][sq] = tv0.x; Ts[sc*8+1][sq] = tv0.y;
            Ts[sc*8+2][sq] = tv0.z; Ts[sc*8+3][sq] = tv0.w;
            Ts[sc*8+4][sq] = tv1.x; Ts[sc*8+5][sq] = tv1.y;
            Ts[sc*8+6][sq] = tv1.z; Ts[sc*8+7][sq] = tv1.w;
            __syncthreads();
#pragma unroll
            for (int k = 0; k < FB_KT; ++k) {
                const float4 av = *(const float4*)&Xs[k][ty * 4];
                const float4 bv = *(const float4*)&Ts[k][tx * 4];
                float a[4] = {av.x, av.y, av.z, av.w};
                float b[4] = {bv.x, bv.y, bv.z, bv.w};
#pragma unroll
                for (int i = 0; i < 4; ++i)
#pragma unroll
                    for (int j = 0; j < 4; ++j)
                        acc[i][j] = fmaf(a[i], b[j], acc[i][j]);
            }
        }
#pragma unroll
        for (int j = 0; j < 4; ++j) {
            int tcol = c0 + s + tx * 4 + j;
            float tt = t2[tcol];
#pragma unroll
            for (int i = 0; i < 4; ++i)
                ins5(bd[i], bi_[i], fmaf(-2.0f, acc[i][j], tt), tcol);
        }
    }
    __syncthreads();
#pragma unroll
    for (int i = 0; i < 4; ++i)
#pragma unroll
        for (int k = 0; k < KNN; ++k) {
            MD[ty * 4 + i][tx * KNN + k] = bd[i][k];
            MI[ty * 4 + i][tx * KNN + k] = bi_[i][k];
        }
    __syncthreads();
    if (tid < FB_QT) {
        int q = q0 + tid;
        for (int k = 0; k < KNN; ++k) {
            float best = 3.4e38f; int bidx = 0x7fffffff; int bj = -1;
            for (int j = 0; j < 16 * KNN; ++j) {
                float dv = MD[tid][j]; int iv = MI[tid][j];
                if (dv < best || (dv == best && iv < bidx)) { best = dv; bidx = iv; bj = j; }
            }
            MD[tid][bj] = 3.4e38f;
            candD[((size_t)q * FB_NCHUNK + blockIdx.y) * KNN + k] = best;
            candI[((size_t)q * FB_NCHUNK + blockIdx.y) * KNN + k] = bidx;
        }
    }
}

__global__ __launch_bounds__(256)
void fb_knn_final(const float* __restrict__ candD, const int* __restrict__ candI,
                  const int* __restrict__ y, int* __restrict__ out) {
    int q = blockIdx.x * 256 + threadIdx.x;
    if (q >= NQ) return;
    bool is64 = true;
#pragma unroll
    for (int i = 1; i < 64; i += 2) is64 = is64 && (y[i] == 0);
    float bd[KNN]; int bi_[KNN];
#pragma unroll
    for (int k = 0; k < KNN; ++k) { bd[k] = 3.4e38f; bi_[k] = 0x7fffffff; }
    for (int c = 0; c < FB_NCHUNK * KNN; ++c)
        ins5(bd, bi_, candD[(size_t)q * FB_NCHUNK * KNN + c], candI[(size_t)q * FB_NCHUNK * KNN + c]);
    int lab[KNN];
#pragma unroll
    for (int k = 0; k < KNN; ++k) lab[k] = is64 ? y[2 * bi_[k]] : y[bi_[k]];
    int bestLab = 0x7fffffff, bestC = 0;
#pragma unroll
    for (int i = 0; i < KNN; ++i) {
        int c = 0;
#pragma unroll
        for (int j = 0; j < KNN; ++j) c += (lab[j] == lab[i]);
        if (c > bestC || (c == bestC && lab[i] < bestLab)) { bestC = c; bestLab = lab[i]; }
    }
    out[q] = bestLab;
}

// =================== launch ===================
extern "C" void kernel_launch(void* const* d_in, const int* in_sizes, int n_in,
                              void* d_out, int out_size, void* d_ws, size_t ws_size,
                              hipStream_t stream) {
    const float* x  = (const float*)d_in[0];
    const float* xt = (const float*)d_in[1];
    const int*   y  = (const int*)d_in[2];
    int* out = (int*)d_out;

    // layout: xt_perm 64MB | x_perm 2MB | t2 256KB | candD 1.31MB | candI 1.31MB
    const size_t REQ = 72089600ull;
    if (ws_size >= REQ) {
        char* ws = (char*)d_ws;
        unsigned short* xt_pm = (unsigned short*)ws;
        unsigned short* x_pm  = (unsigned short*)(ws + 67108864);
        float*          t2    = (float*)(ws + 69206016);
        float*          candD = (float*)(ws + 69468160);
        int*            candI = (int*)(ws + 70778880);

        hipLaunchKernelGGL(conv_perm_kernel, dim3(NTRAIN / 16), dim3(256), 0, stream, xt, xt_pm);
        hipLaunchKernelGGL(conv_perm_kernel, dim3(NQ / 16), dim3(256), 0, stream, x, x_pm);
        hipLaunchKernelGGL(t2_kernel, dim3(NTRAIN / 4), dim3(256), 0, stream, xt, t2);
        hipLaunchKernelGGL(knn_filter, dim3(NQT2 * NGRP), dim3(1024), 0, stream,
                           x_pm, xt_pm, t2, candD, candI);
        hipLaunchKernelGGL(knn_refine, dim3(NQ), dim3(256), 0, stream,
                           x, xt, t2, candD, candI, y, out);
    } else {
        float* ws    = (float*)d_ws;
        float* t2    = ws;
        float* candD = ws + NTRAIN;
        int*   candI = (int*)(ws + NTRAIN + (size_t)NQ * FB_NCHUNK * KNN);
        hipLaunchKernelGGL(t2_kernel, dim3(NTRAIN / 4), dim3(256), 0, stream, xt, t2);
        hipLaunchKernelGGL(fb_knn_partial, dim3(NQ / FB_QT, FB_NCHUNK), dim3(256), 0, stream,
                           x, xt, t2, candD, candI);
        hipLaunchKernelGGL(fb_knn_final, dim3(NQ / 256), dim3(256), 0, stream,
                           candD, candI, y, out);
    }
}

// Round 13
// 440.463 us; speedup vs baseline: 1.7167x; 1.7167x over previous
//
#include <hip/hip_runtime.h>

#define NTRAIN 65536
#define NQ     2048
#define KD     512
#define KNN    5

// ---------------- filter config: 256q x 2048t per block, 16 waves, fp8 no-LDS GEMM --------
#define QT2 256                  // queries per block
#define TPB 2048                 // train rows per block
#define CH 256                   // chunk size (fold granularity)
#define NGRP (NTRAIN / TPB)      // 32 train groups
#define NQT2 (NQ / QT2)          // 8 query tiles
#define NSLOT (NGRP * KNN)       // 160 cand entries per query
#define MARGIN 36.0f             // fp8 filter margin (2x max |score err| ~13 + slack)
#define CAP 192

typedef float f32x4 __attribute__((ext_vector_type(4)));
typedef long lx2 __attribute__((ext_vector_type(2)));

__device__ inline unsigned short f2bf(float f) {
    unsigned u = __float_as_uint(f);
    unsigned r = u + 0x7fffu + ((u >> 16) & 1u);
    return (unsigned short)(r >> 16);
}

template<int KK>
__device__ inline void ins5(float (&bd)[KK], int (&bi)[KK], float nd, int ni) {
    if (nd < bd[KK-1] || (nd == bd[KK-1] && ni < bi[KK-1])) {
#pragma unroll
        for (int k = 0; k < KK; ++k) {
            bool sw = (nd < bd[k]) || (nd == bd[k] && ni < bi[k]);
            float od = bd[k]; int oi = bi[k];
            bd[k] = sw ? nd : od; bi[k] = sw ? ni : oi;
            nd = sw ? od : nd;    ni = sw ? oi : ni;
        }
    }
}

__device__ inline void ins5v(float (&b5)[KNN], float v) {
    if (v < b5[KNN-1]) {
#pragma unroll
        for (int k = 0; k < KNN; ++k) {
            bool sw = v < b5[k];
            float o = b5[k];
            b5[k] = sw ? v : o;
            v = sw ? o : v;
        }
    }
}

// ---------------- t2: EXACT round-1 arithmetic (proven r4-r12) ----------------
__global__ __launch_bounds__(256)
void t2_kernel(const float* __restrict__ xt, float* __restrict__ t2) {
    int row  = blockIdx.x * 4 + (threadIdx.x >> 6);
    int lane = threadIdx.x & 63;
    const float4* p = (const float4*)(xt + (size_t)row * KD);
    float s = 0.f;
#pragma unroll
    for (int c = 0; c < 2; ++c) {
        float4 v = p[lane + c * 64];
        s += v.x * v.x + v.y * v.y + v.z * v.z + v.w * v.w;
    }
#pragma unroll
    for (int off = 32; off; off >>= 1) s += __shfl_down(s, off);
    if (lane == 0) t2[row] = s;
}

// ---------------- conv: fp32 row-major -> fp8 e4m3 paired-unit frag-major ----------------
// unit U = ((rg>>4)*16 + kt)*16 + (rg&15); lane l of U: row rg*16+(l&15), k kt*32+(l>>4)*8..+8
// paired store: byte addr = (U>>1)*1024 + l*16 + (U&1)*8  (so one uint4 load serves 2 units)
__global__ __launch_bounds__(256)
void conv_perm_fp8(const float* __restrict__ in, unsigned char* __restrict__ outp) {
    __shared__ float tile[16][512];               // 32 KB fp32 tile
    const int rg = blockIdx.x, t = threadIdx.x;
    const int row_l = t >> 4, sub = t & 15;

    const float* rp = in + ((size_t)rg * 16 + row_l) * KD + sub * 4;
#pragma unroll
    for (int j = 0; j < 8; ++j) {
        float4 v = *(const float4*)(rp + j * 64);
        *(float4*)&tile[row_l][sub * 4 + j * 64] = v;
    }
    __syncthreads();

#pragma unroll
    for (int i = 0; i < 4; ++i) {
        const int sl = t + i * 256;               // 1024 lane-slots
        const int kt = sl >> 6, l = sl & 63;
        const int row = l & 15;
        const int kb  = kt * 32 + ((l >> 4) << 3);
        const float* f = &tile[row][kb];
        unsigned int w0 = 0, w1 = 0;
        w0 = __builtin_amdgcn_cvt_pk_fp8_f32(f[0], f[1], w0, false);
        w0 = __builtin_amdgcn_cvt_pk_fp8_f32(f[2], f[3], w0, true);
        w1 = __builtin_amdgcn_cvt_pk_fp8_f32(f[4], f[5], w1, false);
        w1 = __builtin_amdgcn_cvt_pk_fp8_f32(f[6], f[7], w1, true);
        const int U = ((rg >> 4) * 16 + kt) * 16 + (rg & 15);
        unsigned int* dst = (unsigned int*)(outp + (size_t)(U >> 1) * 1024 + l * 16 + (U & 1) * 8);
        dst[0] = w0; dst[1] = w1;
    }
}

// ---------------- filter: barrier-free direct-to-register fp8 MFMA GEMM (r10 structure) ----
__global__ __launch_bounds__(1024)
void knn_filter(const unsigned char* __restrict__ xperm, const unsigned char* __restrict__ xtperm,
                const float* __restrict__ t2g,
                float* __restrict__ candD, int* __restrict__ candI) {
    __shared__ __align__(16) char smem[81920];    // merge only

    const int tid  = threadIdx.x;
    const int w    = tid >> 6, lane = tid & 63;
    const int wm   = w & 3,  wn = w >> 2;         // wm: train quarter(64), wn: query quarter(64)
    const int lrow = lane & 15, lhi = lane >> 4;

    const int qt   = blockIdx.x >> 5;             // 0..7  (r10-proven mapping)
    const int grp  = blockIdx.x & 31;             // 0..31
    const int q0   = qt * QT2;
    const int row0 = grp * TPB;

    const char* Au = (const char*)xtperm + (size_t)grp * 1048576;   // 2048 units * 512B
    const char* Bu = (const char*)xperm  + (size_t)qt  * 131072;    // 256 units * 512B
    const int laneOff = lane * 16;

    f32x4 acc[4][4];
#pragma unroll
    for (int m = 0; m < 4; ++m)
#pragma unroll
        for (int n = 0; n < 4; ++n) acc[m][n] = 0.f;

    float bd[4][KNN]; int bi[4][KNN];
#pragma unroll
    for (int n = 0; n < 4; ++n)
#pragma unroll
        for (int k = 0; k < KNN; ++k) { bd[n][k] = 3.4e38f; bi[n][k] = 0x7fffffff; }

    for (int ch = 0; ch < 8; ++ch) {
#pragma unroll 2
        for (int kt = 0; kt < 16; ++kt) {
            const int s = ch * 16 + kt;
            const char* Ak = Au + (size_t)(s * 8 + wm * 2) * 1024 + laneOff;
            const char* Bk = Bu + (size_t)(kt * 8 + wn * 2) * 1024 + laneOff;
            lx2 A0 = *(const lx2*)(Ak);
            lx2 A1 = *(const lx2*)(Ak + 1024);
            lx2 B0 = *(const lx2*)(Bk);
            lx2 B1 = *(const lx2*)(Bk + 1024);
            long a0 = A0.x, a1 = A0.y, a2 = A1.x, a3 = A1.y;
            long b0 = B0.x, b1 = B0.y, b2 = B1.x, b3 = B1.y;
            acc[0][0] = __builtin_amdgcn_mfma_f32_16x16x32_fp8_fp8(a0, b0, acc[0][0], 0, 0, 0);
            acc[0][1] = __builtin_amdgcn_mfma_f32_16x16x32_fp8_fp8(a0, b1, acc[0][1], 0, 0, 0);
            acc[0][2] = __builtin_amdgcn_mfma_f32_16x16x32_fp8_fp8(a0, b2, acc[0][2], 0, 0, 0);
            acc[0][3] = __builtin_amdgcn_mfma_f32_16x16x32_fp8_fp8(a0, b3, acc[0][3], 0, 0, 0);
            acc[1][0] = __builtin_amdgcn_mfma_f32_16x16x32_fp8_fp8(a1, b0, acc[1][0], 0, 0, 0);
            acc[1][1] = __builtin_amdgcn_mfma_f32_16x16x32_fp8_fp8(a1, b1, acc[1][1], 0, 0, 0);
            acc[1][2] = __builtin_amdgcn_mfma_f32_16x16x32_fp8_fp8(a1, b2, acc[1][2], 0, 0, 0);
            acc[1][3] = __builtin_amdgcn_mfma_f32_16x16x32_fp8_fp8(a1, b3, acc[1][3], 0, 0, 0);
            acc[2][0] = __builtin_amdgcn_mfma_f32_16x16x32_fp8_fp8(a2, b0, acc[2][0], 0, 0, 0);
            acc[2][1] = __builtin_amdgcn_mfma_f32_16x16x32_fp8_fp8(a2, b1, acc[2][1], 0, 0, 0);
            acc[2][2] = __builtin_amdgcn_mfma_f32_16x16x32_fp8_fp8(a2, b2, acc[2][2], 0, 0, 0);
            acc[2][3] = __builtin_amdgcn_mfma_f32_16x16x32_fp8_fp8(a2, b3, acc[2][3], 0, 0, 0);
            acc[3][0] = __builtin_amdgcn_mfma_f32_16x16x32_fp8_fp8(a3, b0, acc[3][0], 0, 0, 0);
            acc[3][1] = __builtin_amdgcn_mfma_f32_16x16x32_fp8_fp8(a3, b1, acc[3][1], 0, 0, 0);
            acc[3][2] = __builtin_amdgcn_mfma_f32_16x16x32_fp8_fp8(a3, b2, acc[3][2], 0, 0, 0);
            acc[3][3] = __builtin_amdgcn_mfma_f32_16x16x32_fp8_fp8(a3, b3, acc[3][3], 0, 0, 0);
        }

        // wave-local chunk fold (identical to r10)
        {
            const int c0  = row0 + ch * CH;
            const int rbl = wm * 64 + lhi * 4;
#pragma unroll
            for (int m = 0; m < 4; ++m) {
                const float4 t2v = *(const float4*)(t2g + c0 + rbl + m * 16);
#pragma unroll
                for (int n = 0; n < 4; ++n)
#pragma unroll
                    for (int r2 = 0; r2 < 4; ++r2) {
                        float sc = fmaf(-2.f, acc[m][n][r2], (&t2v.x)[r2]);
                        ins5(bd[n], bi[n], sc, c0 + rbl + m * 16 + r2);
                    }
            }
#pragma unroll
            for (int m = 0; m < 4; ++m)
#pragma unroll
                for (int n = 0; n < 4; ++n) acc[m][n] = 0.f;
        }
    }

    // ---- block merge: 16 slots x top-5 per query, two 128-query half passes (r10-proven) ----
    float* MD = (float*)smem;                      // [128][80] = 40 KB
    int*   MI = (int*)(smem + 40960);              // [128][80] = 40 KB
    const int slot = wm * 4 + lhi;                 // 0..15
#pragma unroll
    for (int half = 0; half < 2; ++half) {
        __syncthreads();
#pragma unroll
        for (int n = 0; n < 4; ++n) {
            const int ql = wn * 64 + n * 16 + lrow;    // 0..255
            if ((ql >> 7) == half) {
#pragma unroll
                for (int k = 0; k < KNN; ++k) {
                    MD[(ql & 127) * 80 + slot * KNN + k] = bd[n][k];
                    MI[(ql & 127) * 80 + slot * KNN + k] = bi[n][k];
                }
            }
        }
        __syncthreads();
        if (tid < 128) {
            float fd[KNN]; int fi[KNN];
#pragma unroll
            for (int k = 0; k < KNN; ++k) { fd[k] = 3.4e38f; fi[k] = 0x7fffffff; }
            for (int j = 0; j < 16 * KNN; ++j) ins5(fd, fi, MD[tid * 80 + j], MI[tid * 80 + j]);
            size_t base = ((size_t)(q0 + half * 128 + tid) * NGRP + grp) * KNN;
#pragma unroll
            for (int k = 0; k < KNN; ++k) { candD[base + k] = fd[k]; candI[base + k] = fi[k]; }
        }
    }
}

// ---------------- refine: global approx top-5 -> T=a5+MARGIN -> exact rerank -> vote ------
__global__ __launch_bounds__(256)
void knn_refine(const float* __restrict__ x, const float* __restrict__ xt,
                const float* __restrict__ t2,
                const float* __restrict__ candD, const int* __restrict__ candI,
                const int* __restrict__ y, int* __restrict__ out) {
    __shared__ float sv[256 * KNN];
    __shared__ float sv2[64 * KNN];
    __shared__ float xl[KD];
    __shared__ int   lidx[CAP];
    __shared__ float lex[CAP];
    __shared__ int   lcount;
    __shared__ float sT;

    const int q = blockIdx.x, tid = threadIdx.x;
    const float* cd = candD + (size_t)q * NSLOT;
    const int*   ci = candI + (size_t)q * NSLOT;

    for (int i = tid; i < KD; i += 256) xl[i] = x[(size_t)q * KD + i];

    float b5[KNN];
#pragma unroll
    for (int k = 0; k < KNN; ++k) b5[k] = 3.4e38f;
    for (int j = tid; j < NSLOT; j += 256) ins5v(b5, cd[j]);
#pragma unroll
    for (int k = 0; k < KNN; ++k) sv[tid * KNN + k] = b5[k];
    __syncthreads();

    if (tid < 64) {
#pragma unroll
        for (int k = 0; k < KNN; ++k) b5[k] = 3.4e38f;
        for (int t = 0; t < 4; ++t)
#pragma unroll
            for (int k = 0; k < KNN; ++k) ins5v(b5, sv[(tid * 4 + t) * KNN + k]);
#pragma unroll
        for (int k = 0; k < KNN; ++k) sv2[tid * KNN + k] = b5[k];
    }
    __syncthreads();

    if (tid == 0) {
#pragma unroll
        for (int k = 0; k < KNN; ++k) b5[k] = 3.4e38f;
        for (int j = 0; j < 64 * KNN; ++j) ins5v(b5, sv2[j]);
        sT = b5[KNN - 1] + MARGIN;
        lcount = 0;
    }
    __syncthreads();
    float T = sT;

    for (int j = tid; j < NSLOT; j += 256) {
        if (cd[j] <= T) {
            int p = atomicAdd(&lcount, 1);
            if (p < CAP) lidx[p] = ci[j];
        }
    }
    __syncthreads();
    int Q = min(lcount, CAP);

    // exact rerank: one thread per candidate, sequential fmaf over k (round-1 order)
    for (int j = tid; j < Q; j += 256) {
        int c = lidx[j];
        const float* tr = xt + (size_t)c * KD;
        float s = 0.f;
        for (int k = 0; k < KD; ++k) s = fmaf(xl[k], tr[k], s);
        lex[j] = fmaf(-2.f, s, t2[c]);
    }
    __syncthreads();

    if (tid == 0) {
        bool is64 = true;
#pragma unroll
        for (int i = 1; i < 64; i += 2) is64 = is64 && (y[i] == 0);
        float fd[KNN]; int fi[KNN];
#pragma unroll
        for (int k = 0; k < KNN; ++k) { fd[k] = 3.4e38f; fi[k] = 0x7fffffff; }
        for (int j = 0; j < Q; ++j) ins5(fd, fi, lex[j], lidx[j]);
        int lab[KNN];
#pragma unroll
        for (int k = 0; k < KNN; ++k) lab[k] = is64 ? y[2 * fi[k]] : y[fi[k]];
        int bestLab = 0x7fffffff, bestC = 0;
#pragma unroll
        for (int i = 0; i < KNN; ++i) {
            int c = 0;
#pragma unroll
            for (int j = 0; j < KNN; ++j) c += (lab[j] == lab[i]);
            if (c > bestC || (c == bestC && lab[i] < bestLab)) { bestC = c; bestLab = lab[i]; }
        }
        out[q] = bestLab;
    }
}

// =================== round-1 fp32 fallback (small ws) ===================
#define FB_QT 64
#define FB_TT 64
#define FB_KT 32
#define FB_NCHUNK 32
#define FB_CHUNK (NTRAIN / FB_NCHUNK)

__global__ __launch_bounds__(256)
void fb_knn_partial(const float* __restrict__ x, const float* __restrict__ xt,
                    const float* __restrict__ t2,
                    float* __restrict__ candD, int* __restrict__ candI) {
    __shared__ __align__(16) float smem[FB_QT * 81 * 2];
    float (*Xs)[FB_QT + 4] = (float (*)[FB_QT + 4])smem;
    float (*Ts)[FB_TT + 4] = (float (*)[FB_TT + 4])(smem + FB_KT * (FB_QT + 4));
    float (*MD)[81]     = (float (*)[81])smem;
    int   (*MI)[81]     = (int   (*)[81])(smem + FB_QT * 81);

    const int tid = threadIdx.x;
    const int tx = tid & 15, ty = tid >> 4;
    const int q0 = blockIdx.x * FB_QT;
    const int c0 = blockIdx.y * FB_CHUNK;
    const int sq = tid >> 2, sc = tid & 3;

    float bd[4][KNN]; int bi_[4][KNN];
#pragma unroll
    for (int i = 0; i < 4; ++i)
#pragma unroll
        for (int k = 0; k < KNN; ++k) { bd[i][k] = 3.4e38f; bi_[i][k] = 0x7fffffff; }

    const float* xrow = x + (size_t)(q0 + sq) * KD;

    for (int s = 0; s < FB_CHUNK; s += FB_TT) {
        float acc[4][4];
#pragma unroll
        for (int i = 0; i < 4; ++i)
#pragma unroll
            for (int j = 0; j < 4; ++j) acc[i][j] = 0.f;
        const float* trow = xt + (size_t)(c0 + s + sq) * KD;
        for (int kt = 0; kt < KD; kt += FB_KT) {
            float4 xv0 = *(const float4*)(xrow + kt + sc * 8);
            float4 xv1 = *(const float4*)(xrow + kt + sc * 8 + 4);
            float4 tv0 = *(const float4*)(trow + kt + sc * 8);
            float4 tv1 = *(const float4*)(trow + kt + sc * 8 + 4);
            __syncthreads();
            Xs[sc*8+0][sq] = xv0.x; Xs[sc*8+1][sq] = xv0.y;
            Xs[sc*8+2][sq] = xv0.z; Xs[sc*8+3][sq] = xv0.w;
            Xs[sc*8+4][sq] = xv1.x; Xs[sc*8+5][sq] = xv1.y;
            Xs[sc*8+6][sq] = xv1.z; Xs[sc*8+7][sq] = xv1.w;
            Ts[sc*8+0][sq] = tv0.x; Ts[sc*8+1][sq] = tv0.y;
            Ts[sc*8+2][sq] = tv0.z; Ts[sc*8+3][sq] = tv0.w;
            Ts[sc*8+4][sq] = tv1.x; Ts[sc*8+5][sq] = tv1.y;
            Ts[sc*8+6][sq] = tv1.z; Ts[sc*8+7][sq] = tv1.w;
            __syncthreads();
#pragma unroll
            for (int k = 0; k < FB_KT; ++k) {
                const float4 av = *(const float4*)&Xs[k][ty * 4];
                const float4 bv = *(const float4*)&Ts[k][tx * 4];
                float a[4] = {av.x, av.y, av.z, av.w};
                float b[4] = {bv.x, bv.y, bv.z, bv.w};
#pragma unroll
                for (int i = 0; i < 4; ++i)
#pragma unroll
                    for (int j = 0; j < 4; ++j)
                        acc[i][j] = fmaf(a[i], b[j], acc[i][j]);
            }
        }
#pragma unroll
        for (int j = 0; j < 4; ++j) {
            int tcol = c0 + s + tx * 4 + j;
            float tt = t2[tcol];
#pragma unroll
            for (int i = 0; i < 4; ++i)
                ins5(bd[i], bi_[i], fmaf(-2.0f, acc[i][j], tt), tcol);
        }
    }
    __syncthreads();
#pragma unroll
    for (int i = 0; i < 4; ++i)
#pragma unroll
        for (int k = 0; k < KNN; ++k) {
            MD[ty * 4 + i][tx * KNN + k] = bd[i][k];
            MI[ty * 4 + i][tx * KNN + k] = bi_[i][k];
        }
    __syncthreads();
    if (tid < FB_QT) {
        int q = q0 + tid;
        for (int k = 0; k < KNN; ++k) {
            float best = 3.4e38f; int bidx = 0x7fffffff; int bj = -1;
            for (int j = 0; j < 16 * KNN; ++j) {
                float dv = MD[tid][j]; int iv = MI[tid][j];
                if (dv < best || (dv == best && iv < bidx)) { best = dv; bidx = iv; bj = j; }
            }
            MD[tid][bj] = 3.4e38f;
            candD[((size_t)q * FB_NCHUNK + blockIdx.y) * KNN + k] = best;
            candI[((size_t)q * FB_NCHUNK + blockIdx.y) * KNN + k] = bidx;
        }
    }
}

__global__ __launch_bounds__(256)
void fb_knn_final(const float* __restrict__ candD, const int* __restrict__ candI,
                  const int* __restrict__ y, int* __restrict__ out) {
    int q = blockIdx.x * 256 + threadIdx.x;
    if (q >= NQ) return;
    bool is64 = true;
#pragma unroll
    for (int i = 1; i < 64; i += 2) is64 = is64 && (y[i] == 0);
    float bd[KNN]; int bi_[KNN];
#pragma unroll
    for (int k = 0; k < KNN; ++k) { bd[k] = 3.4e38f; bi_[k] = 0x7fffffff; }
    for (int c = 0; c < FB_NCHUNK * KNN; ++c)
        ins5(bd, bi_, candD[(size_t)q * FB_NCHUNK * KNN + c], candI[(size_t)q * FB_NCHUNK * KNN + c]);
    int lab[KNN];
#pragma unroll
    for (int k = 0; k < KNN; ++k) lab[k] = is64 ? y[2 * bi_[k]] : y[bi_[k]];
    int bestLab = 0x7fffffff, bestC = 0;
#pragma unroll
    for (int i = 0; i < KNN; ++i) {
        int c = 0;
#pragma unroll
        for (int j = 0; j < KNN; ++j) c += (lab[j] == lab[i]);
        if (c > bestC || (c == bestC && lab[i] < bestLab)) { bestC = c; bestLab = lab[i]; }
    }
    out[q] = bestLab;
}

// =================== launch ===================
extern "C" void kernel_launch(void* const* d_in, const int* in_sizes, int n_in,
                              void* d_out, int out_size, void* d_ws, size_t ws_size,
                              hipStream_t stream) {
    const float* x  = (const float*)d_in[0];
    const float* xt = (const float*)d_in[1];
    const int*   y  = (const int*)d_in[2];
    int* out = (int*)d_out;

    // layout: xt_fp8 32MB | x_fp8 1MB | t2 256KB | candD 1.31MB | candI 1.31MB
    const size_t REQ = 37486592ull;
    if (ws_size >= REQ) {
        char* ws = (char*)d_ws;
        unsigned char* xt8 = (unsigned char*)ws;
        unsigned char* x8  = (unsigned char*)(ws + 33554432);
        float*         t2    = (float*)(ws + 34603008);
        float*         candD = (float*)(ws + 34865152);
        int*           candI = (int*)(ws + 36175872);

        hipLaunchKernelGGL(conv_perm_fp8, dim3(NTRAIN / 16), dim3(256), 0, stream, xt, xt8);
        hipLaunchKernelGGL(conv_perm_fp8, dim3(NQ / 16), dim3(256), 0, stream, x, x8);
        hipLaunchKernelGGL(t2_kernel, dim3(NTRAIN / 4), dim3(256), 0, stream, xt, t2);
        hipLaunchKernelGGL(knn_filter, dim3(NQT2 * NGRP), dim3(1024), 0, stream,
                           x8, xt8, t2, candD, candI);
        hipLaunchKernelGGL(knn_refine, dim3(NQ), dim3(256), 0, stream,
                           x, xt, t2, candD, candI, y, out);
    } else {
        float* ws    = (float*)d_ws;
        float* t2    = ws;
        float* candD = ws + NTRAIN;
        int*   candI = (int*)(ws + NTRAIN + (size_t)NQ * FB_NCHUNK * KNN);
        hipLaunchKernelGGL(t2_kernel, dim3(NTRAIN / 4), dim3(256), 0, stream, xt, t2);
        hipLaunchKernelGGL(fb_knn_partial, dim3(NQ / FB_QT, FB_NCHUNK), dim3(256), 0, stream,
                           x, xt, t2, candD, candI);
        hipLaunchKernelGGL(fb_knn_final, dim3(NQ / 256), dim3(256), 0, stream,
                           candD, candI, y, out);
    }
}